// Round 2
// 277.104 us; speedup vs baseline: 1.0184x; 1.0184x over previous
//
#include <hip/hip_runtime.h>
#include <stdint.h>
#include <string.h>

// ---------------------------------------------------------------------------
// JAX threefry2x32 (20 rounds), exact reproduction of
// jax/_src/prng.py::_threefry2x32 (partitionable layout).
// Host copy used for the 64-step branch trace.
// ---------------------------------------------------------------------------
static inline uint32_t h_rotl32(uint32_t x, uint32_t r) {
  return (x << r) | (x >> (32u - r));
}

static void h_threefry2x32(uint32_t k0, uint32_t k1, uint32_t x0, uint32_t x1,
                           uint32_t& o0, uint32_t& o1) {
  const uint32_t ks2 = k0 ^ k1 ^ 0x1BD11BDAu;
  x0 += k0; x1 += k1;
  x0 += x1; x1 = h_rotl32(x1, 13); x1 ^= x0;
  x0 += x1; x1 = h_rotl32(x1, 15); x1 ^= x0;
  x0 += x1; x1 = h_rotl32(x1, 26); x1 ^= x0;
  x0 += x1; x1 = h_rotl32(x1,  6); x1 ^= x0;
  x0 += k1; x1 += ks2 + 1u;
  x0 += x1; x1 = h_rotl32(x1, 17); x1 ^= x0;
  x0 += x1; x1 = h_rotl32(x1, 29); x1 ^= x0;
  x0 += x1; x1 = h_rotl32(x1, 16); x1 ^= x0;
  x0 += x1; x1 = h_rotl32(x1, 24); x1 ^= x0;
  x0 += ks2; x1 += k0 + 2u;
  x0 += x1; x1 = h_rotl32(x1, 13); x1 ^= x0;
  x0 += x1; x1 = h_rotl32(x1, 15); x1 ^= x0;
  x0 += x1; x1 = h_rotl32(x1, 26); x1 ^= x0;
  x0 += x1; x1 = h_rotl32(x1,  6); x1 ^= x0;
  x0 += k0; x1 += k1 + 3u;
  x0 += x1; x1 = h_rotl32(x1, 17); x1 ^= x0;
  x0 += x1; x1 = h_rotl32(x1, 29); x1 ^= x0;
  x0 += x1; x1 = h_rotl32(x1, 16); x1 ^= x0;
  x0 += x1; x1 = h_rotl32(x1, 24); x1 ^= x0;
  x0 += k1; x1 += ks2 + 4u;
  x0 += x1; x1 = h_rotl32(x1, 13); x1 ^= x0;
  x0 += x1; x1 = h_rotl32(x1, 15); x1 ^= x0;
  x0 += x1; x1 = h_rotl32(x1, 26); x1 ^= x0;
  x0 += x1; x1 = h_rotl32(x1,  6); x1 ^= x0;
  o0 = x0 + ks2;
  o1 = x1 + k0 + 5u;
}

// ---------------------------------------------------------------------------
// Device: dual interleaved threefry (h-key and e-key ciphers on the same
// counter n), rotates forced to single v_alignbit_b32, fold o0^o1.
// ---------------------------------------------------------------------------
#define TF_R(x0, x1, r)                                   \
  x0 += x1;                                               \
  x1 = __builtin_amdgcn_alignbit(x1, x1, 32u - (r));      \
  x1 ^= x0;

#define TF_G(r1, r2, r3, r4)                              \
  TF_R(a0, a1, r1) TF_R(b0, b1, r1)                       \
  TF_R(a0, a1, r2) TF_R(b0, b1, r2)                       \
  TF_R(a0, a1, r3) TF_R(b0, b1, r3)                       \
  TF_R(a0, a1, r4) TF_R(b0, b1, r4)

__device__ inline void dual_tf_fold(uint32_t hk0, uint32_t hk1, uint32_t hks,
                                    uint32_t ek0, uint32_t ek1, uint32_t eks,
                                    uint32_t n, uint32_t& oh, uint32_t& oe) {
  uint32_t a0 = hk0, a1 = n + hk1;   // init key injection (x0=0, x1=n)
  uint32_t b0 = ek0, b1 = n + ek1;
  TF_G(13, 15, 26, 6)
  a0 += hk1; a1 += hks + 1u;  b0 += ek1; b1 += eks + 1u;
  TF_G(17, 29, 16, 24)
  a0 += hks; a1 += hk0 + 2u;  b0 += eks; b1 += ek0 + 2u;
  TF_G(13, 15, 26, 6)
  a0 += hk0; a1 += hk1 + 3u;  b0 += ek0; b1 += ek1 + 3u;
  TF_G(17, 29, 16, 24)
  a0 += hk1; a1 += hks + 4u;  b0 += ek1; b1 += eks + 4u;
  TF_G(13, 15, 26, 6)
  oh = (a0 + hks) ^ (a1 + hk0 + 5u);
  oe = (b0 + eks) ^ (b1 + ek0 + 5u);
}

// ---------------------------------------------------------------------------
// Kernel parameters: keys + FS-prescaled Giles erfinv coefficients.
// Coefficients as kernel args => guaranteed SGPR residence (one s_load in the
// preamble), every poly step is a single v_fma_f32 v,v,s,v (1 SGPR read: ok).
// ---------------------------------------------------------------------------
struct GenParams {
  uint32_t kh0, kh1, khs, ke0, ke1, kes;
  int n4;
  float lo;       // -0.99999994f  (nextafterf(-1,0), matches jax uniform lo)
  float negln2;   // -ln(2): w = -ln(1-t) = log2(1-t) * negln2
  float m25;      // -2.5f
  float m3;       // -3.0f
  float c[9];     // central-branch Giles coeffs, FS-prescaled
  float t9[9];    // tail-branch Giles coeffs, FS-prescaled
};

// One word -> (p', u) with p' already FS-scaled; normal*FS = p'*u.
__device__ inline void word_to_pu(uint32_t bits, const GenParams& P,
                                  float& p, float& u) {
  // (bits>>9) | 0x3f800000 in ONE v_alignbit_b32: (127<<23) | (bits>>9)
  float x = __uint_as_float(__builtin_amdgcn_alignbit(127u, bits, 9u)); // 1+f
  float f = x - 1.0f;                      // [0,1) exact
  // f >= 0 => RN(2f+lo) >= lo; the reference fmax(lo, .) is a provable no-op.
  u = __builtin_fmaf(f, 2.0f, P.lo);
  float t = u * u;
  float L2 = __log2f(1.0f - t);            // w = -ln(1-t) = L2 * negln2
  float ww = __builtin_fmaf(L2, P.negln2, P.m25);   // w - 2.5 (central arg)
  float q = P.c[0];
  q = __builtin_fmaf(q, ww, P.c[1]);
  q = __builtin_fmaf(q, ww, P.c[2]);
  q = __builtin_fmaf(q, ww, P.c[3]);
  q = __builtin_fmaf(q, ww, P.c[4]);
  q = __builtin_fmaf(q, ww, P.c[5]);
  q = __builtin_fmaf(q, ww, P.c[6]);
  q = __builtin_fmaf(q, ww, P.c[7]);
  q = __builtin_fmaf(q, ww, P.c[8]);
  // tail: w >= 5  <=>  L2 <= -5/ln2.  ~0.34% of lanes; exec-masked rare branch.
  if (L2 <= -7.2134752f) {
    float w = L2 * P.negln2;
    float ws = sqrtf(w) + P.m3;            // sqrt(w) - 3
    float q2 = P.t9[0];
    q2 = __builtin_fmaf(q2, ws, P.t9[1]);
    q2 = __builtin_fmaf(q2, ws, P.t9[2]);
    q2 = __builtin_fmaf(q2, ws, P.t9[3]);
    q2 = __builtin_fmaf(q2, ws, P.t9[4]);
    q2 = __builtin_fmaf(q2, ws, P.t9[5]);
    q2 = __builtin_fmaf(q2, ws, P.t9[6]);
    q2 = __builtin_fmaf(q2, ws, P.t9[7]);
    q2 = __builtin_fmaf(q2, ws, P.t9[8]);
    q = q2;
  }
  p = q;
}

// out[n] = FS*(normal_h[n] + normal_e[n]) = p'_h*u_h + p'_e*u_e
__global__ __launch_bounds__(256) void gen_kernel(float* __restrict__ out,
                                                  GenParams P) {
  int tid = blockIdx.x * 256 + threadIdx.x;
  if (tid >= P.n4) return;
  uint32_t base = (uint32_t)tid * 4u;
  float r[4];
#pragma unroll
  for (int j = 0; j < 4; ++j) {
    uint32_t oh, oe;
    dual_tf_fold(P.kh0, P.kh1, P.khs, P.ke0, P.ke1, P.kes,
                 base + (uint32_t)j, oh, oe);
    float ph, uh, pe, ue;
    word_to_pu(oh, P, ph, uh);
    word_to_pu(oe, P, pe, ue);
    r[j] = __builtin_fmaf(ph, uh, pe * ue);   // 2 ops (was mul,mul,add,mul)
  }
  float4 o;
  o.x = r[0]; o.y = r[1]; o.z = r[2]; o.w = r[3];
  reinterpret_cast<float4*>(out)[tid] = o;
}

// fallback: all branches False -> out = (h + e) * 0.7^64
__global__ __launch_bounds__(256) void blend_kernel(
    const float4* __restrict__ a, const float4* __restrict__ b,
    float4* __restrict__ out, float s, int n4) {
  int t = blockIdx.x * 256 + threadIdx.x;
  if (t >= n4) return;
  float4 x = a[t], y = b[t];
  float4 o;
  o.x = (x.x + y.x) * s;
  o.y = (x.y + y.y) * s;
  o.z = (x.z + y.z) * s;
  o.w = (x.w + y.w) * s;
  out[t] = o;
}

extern "C" void kernel_launch(void* const* d_in, const int* in_sizes, int n_in,
                              void* d_out, int out_size, void* d_ws,
                              size_t ws_size, hipStream_t stream) {
  const float* h_in = (const float*)d_in[0];
  const float* e_in = (const float*)d_in[1];
  float* out = (float*)d_out;

  // Host-side deterministic trace of the 64 scan steps (identical every call).
  // base key = jax.random.key(42) -> (0, 42); partitionable split:
  // key_i = enc(key; 0, i); split(key_i,3) -> counters 0,1,2;
  // uniform bits = lane0 ^ lane1 of enc(kb; 0, 0).
  const uint32_t bk0 = 0u, bk1 = 42u;
  int last_true = -1;
  uint32_t kh0 = 0, kh1 = 0, ke0 = 0, ke1 = 0;
  for (uint32_t i = 0; i < 64; ++i) {
    uint32_t ki0, ki1;
    h_threefry2x32(bk0, bk1, 0u, i, ki0, ki1);
    uint32_t kb0, kb1, tkh0, tkh1, tke0, tke1;
    h_threefry2x32(ki0, ki1, 0u, 0u, kb0, kb1);
    h_threefry2x32(ki0, ki1, 0u, 1u, tkh0, tkh1);
    h_threefry2x32(ki0, ki1, 0u, 2u, tke0, tke1);
    uint32_t ub0, ub1;
    h_threefry2x32(kb0, kb1, 0u, 0u, ub0, ub1);
    uint32_t bits = ub0 ^ ub1;
    uint32_t fb = (bits >> 9) | 0x3f800000u;
    float f;
    memcpy(&f, &fb, 4);
    f -= 1.0f;  // uniform in [0,1)
    if (f < 0.5f) {  // RAND_RATIO
      last_true = (int)i;
      kh0 = tkh0; kh1 = tkh1; ke0 = tke0; ke1 = tke1;
    }
  }

  const int n4 = out_size / 4;
  const int grid = (n4 + 255) / 256;

  if (last_true >= 0) {
    const int c = 63 - last_true;
    float scale = 1.0f;
    for (int j = 0; j < c; ++j) scale *= 0.7f;
    const float FS = 1.41421356f * scale;

    static const float C[9] = {
        2.81022636e-08f,  3.43273939e-07f, -3.5233877e-06f,
        -4.39150654e-06f, 0.00021858087f,  -0.00125372503f,
        -0.00417768164f,  0.246640727f,    1.50140941f};
    static const float T[9] = {
        -0.000200214257f, 0.000100950558f, 0.00134934322f,
        -0.00367342844f,  0.00573950773f,  -0.0076224613f,
        0.00943887047f,   1.00167406f,     2.83297682f};

    GenParams P;
    P.kh0 = kh0; P.kh1 = kh1; P.khs = kh0 ^ kh1 ^ 0x1BD11BDAu;
    P.ke0 = ke0; P.ke1 = ke1; P.kes = ke0 ^ ke1 ^ 0x1BD11BDAu;
    P.n4 = n4;
    P.lo = -0.99999994f;
    P.negln2 = -0.69314718f;
    P.m25 = -2.5f;
    P.m3 = -3.0f;
    for (int i = 0; i < 9; ++i) {
      P.c[i] = FS * C[i];   // fold FS into the polynomial (linear in coeffs)
      P.t9[i] = FS * T[i];
    }
    gen_kernel<<<grid, 256, 0, stream>>>(out, P);
  } else {
    float scale = 1.0f;
    for (int j = 0; j < 64; ++j) scale *= 0.7f;
    blend_kernel<<<grid, 256, 0, stream>>>(
        (const float4*)h_in, (const float4*)e_in, (float4*)out, scale, n4);
  }
}